// Round 5
// baseline (400.556 us; speedup 1.0000x reference)
//
#include <hip/hip_runtime.h>

// B=2, H=W=512, 21 classes, 11x11 window, 4x blur. H,W % 4 == 0 -> pad=(0,0),
// avg-pool is exact 4x4 mean, post-upsample crop is identity.
#define NCH 21
#define HWP (1 << 14)   // 128*128
#define KS 11
#define KK 121
// pac v3 tiling: pooled tile 16x8, 4-px strips, 6-ch groups, 128 threads/block
#define PTW 16
#define PTH 8
#define LQW 28                 // padded cols (26 used) -> 112 B rows, 16B-aligned
#define LQH 18
#define LQPLANE (LQW * LQH)    // 504 floats = 2016 B (16B-aligned)
#define LQC 24                 // padded channels (21 used)

// ---- fused: unary = conv3x3(x,w)+b (written); qb = pool4(softmax(unary)) ----
// thread = 4-px row quad; lanes r=0..3 (bits 0-1) cover the 4 rows of a pool block.
__global__ __launch_bounds__(256) void k_conv_sm(const float* __restrict__ x,
                                                 const float* __restrict__ w,
                                                 const float* __restrict__ bias,
                                                 float* __restrict__ unary,
                                                 float* __restrict__ qb) {
    int idx = blockIdx.x * 256 + threadIdx.x;   // 0..131071
    int r = idx & 3;
    int xqi = (idx >> 2) & 127;
    int py = (idx >> 9) & 127;
    int b = idx >> 16;
    int y = 4 * py + r;
    int xq = xqi << 2;

    float p[3][3][6];
#pragma unroll
    for (int ch = 0; ch < 3; ++ch) {
        const float* xp = x + (((size_t)(b * 3 + ch)) << 18);
#pragma unroll
        for (int rr = 0; rr < 3; ++rr) {
            int yy = y + rr - 1;
            if ((unsigned)yy >= 512u) {
#pragma unroll
                for (int j = 0; j < 6; ++j) p[ch][rr][j] = 0.f;
            } else {
                const float* row = xp + (yy << 9);
                float4 v = *(const float4*)(row + xq);
                p[ch][rr][1] = v.x; p[ch][rr][2] = v.y; p[ch][rr][3] = v.z; p[ch][rr][4] = v.w;
                p[ch][rr][0] = (xq > 0) ? row[xq - 1] : 0.f;
                p[ch][rr][5] = (xq + 4 < 512) ? row[xq + 4] : 0.f;
            }
        }
    }
    float a[NCH][4];
    for (int o = 0; o < NCH; ++o) {
        const float* wp = w + o * 27;
        float bz = bias[o];
        float a0 = bz, a1 = bz, a2 = bz, a3 = bz;
#pragma unroll
        for (int ch = 0; ch < 3; ++ch)
#pragma unroll
            for (int rr = 0; rr < 3; ++rr) {
                float w0 = wp[ch * 9 + rr * 3 + 0];
                float w1 = wp[ch * 9 + rr * 3 + 1];
                float w2 = wp[ch * 9 + rr * 3 + 2];
                const float* pr = p[ch][rr];
                a0 += w0 * pr[0] + w1 * pr[1] + w2 * pr[2];
                a1 += w0 * pr[1] + w1 * pr[2] + w2 * pr[3];
                a2 += w0 * pr[2] + w1 * pr[3] + w2 * pr[4];
                a3 += w0 * pr[3] + w1 * pr[4] + w2 * pr[5];
            }
        *(float4*)(unary + (((size_t)(b * NCH + o)) << 18) + (y << 9) + xq) =
            make_float4(a0, a1, a2, a3);
        a[o][0] = a0; a[o][1] = a1; a[o][2] = a2; a[o][3] = a3;
    }
    // softmax per px (4 in-thread) + partial pool
    float qsum[NCH];
#pragma unroll
    for (int c = 0; c < NCH; ++c) qsum[c] = 0.f;
#pragma unroll
    for (int i2 = 0; i2 < 4; ++i2) {
        float m = a[0][i2];
#pragma unroll
        for (int c = 1; c < NCH; ++c) m = fmaxf(m, a[c][i2]);
        float s = 0.f;
#pragma unroll
        for (int c = 0; c < NCH; ++c) { float e = __expf(a[c][i2] - m); a[c][i2] = e; s += e; }
        float inv = 1.0f / s;
#pragma unroll
        for (int c = 0; c < NCH; ++c) qsum[c] += a[c][i2] * inv;
    }
#pragma unroll
    for (int c = 0; c < NCH; ++c) {
        float v = qsum[c];
        v += __shfl_xor(v, 1);
        v += __shfl_xor(v, 2);
        if (r == 0) qb[(((size_t)(b * NCH + c)) << 14) + (py << 7) + xqi] = v * 0.0625f;
    }
}

// ---------------- pooled RGB ----------------
__global__ __launch_bounds__(256) void k_pool_rgb(const float* __restrict__ x,
                                                  float* __restrict__ prgb) {
    int idx = blockIdx.x * 256 + threadIdx.x;   // [b][3][128][128]
    int p = idx & (HWP - 1);
    int ch = (idx >> 14) % 3;
    int b = idx / (3 * HWP);
    int py = p >> 7, px = p & 127;
    const float* xp = x + (((size_t)(b * 3 + ch)) << 18);
    float s = 0.f;
#pragma unroll
    for (int r = 0; r < 4; ++r) {
        const float4 v = *(const float4*)(xp + (((4 * py + r) << 9) + 4 * px));
        s += v.x + v.y + v.z + v.w;
    }
    prgb[idx] = s * 0.0625f;
}

// ---------------- kc = pw0*exp(-.5 s_bil) + pw1*exp(-.5 s_spat) ----------------
__global__ __launch_bounds__(256) void k_build_kc(const float* __restrict__ prgb,
                                                  const float* __restrict__ pw,
                                                  float* __restrict__ kc) {
    int idx = blockIdx.x * 256 + threadIdx.x;   // [b][j][p]
    int p = idx & (HWP - 1);
    int jj = idx >> 14;                          // 0..241
    int b = (jj >= KK) ? 1 : 0;
    int j = jj - KK * b;
    int dy = j / KS, dx = j - dy * KS;
    int py = p >> 7, px = p & 127;
    float pw0 = pw[0], pw1 = pw[1];

    const float inv13 = 1.0f / 13.0f;
    float fy = (4.f * py + 1.5f) * (1.0f / 80.0f);
    float fx = (4.f * px + 1.5f) * (1.0f / 80.0f);
    const float* pb = prgb + (size_t)b * 3 * HWP;
    float r0 = pb[p] * inv13;
    float g0 = pb[HWP + p] * inv13;
    float b0 = pb[2 * HWP + p] * inv13;
    float sy = (4.f * py + 1.5f) * (1.0f / 3.0f);
    float sx = (4.f * px + 1.5f) * (1.0f / 3.0f);

    int ny = py + dy - 5;
    int nx = px + dx - 5;
    float s1, s2;
    if ((unsigned)ny < 128u && (unsigned)nx < 128u) {
        int np = (ny << 7) + nx;
        float r2 = pb[np] * inv13;
        float g2 = pb[HWP + np] * inv13;
        float b2 = pb[2 * HWP + np] * inv13;
        float dya = fy - (4.f * ny + 1.5f) * (1.0f / 80.0f);
        float dxa = fx - (4.f * nx + 1.5f) * (1.0f / 80.0f);
        float dr = r0 - r2, dg = g0 - g2, db = b0 - b2;
        s1 = dya * dya + dxa * dxa + dr * dr + dg * dg + db * db;
        float dys = sy - (4.f * ny + 1.5f) * (1.0f / 3.0f);
        float dxs = sx - (4.f * nx + 1.5f) * (1.0f / 3.0f);
        s2 = dys * dys + dxs * dxs;
    } else {
        s1 = fy * fy + fx * fx + r0 * r0 + g0 * g0 + b0 * b0;  // patch = 0
        s2 = sy * sy + sx * sx;
    }
    kc[idx] = pw0 * __expf(-0.5f * s1) + pw1 * __expf(-0.5f * s2);
}

// ---- pac v3: register-blocked stencil. 256 blocks x 128 thr; 4-px strips, 6-ch groups ----
__global__ __launch_bounds__(128) void k_pac3(const float* __restrict__ qb,
                                              const float* __restrict__ kc,
                                              float* __restrict__ msgc) {
    int tx0 = (blockIdx.x & 7) * PTW;
    int ty0 = ((blockIdx.x >> 3) & 15) * PTH;
    int b = blockIdx.x >> 7;

    __shared__ float lq[LQC * LQPLANE];          // 24*504*4 = 48384 B

    const float* qbb = qb + (((size_t)(b * NCH)) << 14);
    for (int i = threadIdx.x; i < LQC * LQPLANE; i += 128) {
        int c = i / LQPLANE;
        int rem = i - c * LQPLANE;
        int ly = rem / LQW;
        int lx = rem - ly * LQW;
        int gy = ty0 + ly - 5, gx = tx0 + lx - 5;
        float v = 0.f;
        if (c < NCH && (unsigned)gy < 128u && (unsigned)gx < 128u)
            v = qbb[((size_t)c << 14) + (gy << 7) + gx];
        lq[i] = v;
    }
    __syncthreads();

    int g = threadIdx.x >> 5;        // 0..3 -> channels 6g..6g+5
    int s = threadIdx.x & 31;
    int my = s >> 2;                 // 0..7
    int mx0 = (s & 3) << 2;          // 0,4,8,12
    int c0 = g * 6;

    float acc[6][4];
#pragma unroll
    for (int c = 0; c < 6; ++c)
#pragma unroll
        for (int m = 0; m < 4; ++m) acc[c][m] = 0.f;

    int p0 = ((ty0 + my) << 7) + tx0 + mx0;
    const float* kcb = kc + (((size_t)(b * KK)) << 14) + p0;

    for (int dy = 0; dy < KS; ++dy) {
        const float* lrow = lq + c0 * LQPLANE + (my + dy) * LQW + mx0;
        float rb[6][16];
#pragma unroll
        for (int c = 0; c < 6; ++c) {
            const float* lp = lrow + c * LQPLANE;
            float4 v0 = *(const float4*)(lp + 0);
            float4 v1 = *(const float4*)(lp + 4);
            float4 v2 = *(const float4*)(lp + 8);
            float4 v3 = *(const float4*)(lp + 12);
            rb[c][0] = v0.x;  rb[c][1] = v0.y;  rb[c][2] = v0.z;  rb[c][3] = v0.w;
            rb[c][4] = v1.x;  rb[c][5] = v1.y;  rb[c][6] = v1.z;  rb[c][7] = v1.w;
            rb[c][8] = v2.x;  rb[c][9] = v2.y;  rb[c][10] = v2.z; rb[c][11] = v2.w;
            rb[c][12] = v3.x; rb[c][13] = v3.y; rb[c][14] = v3.z; rb[c][15] = v3.w;
        }
#pragma unroll
        for (int dx = 0; dx < KS; ++dx) {
            float4 k4 = *(const float4*)(kcb + (((size_t)(dy * KS + dx)) << 14));
#pragma unroll
            for (int c = 0; c < 6; ++c) {
                acc[c][0] += k4.x * rb[c][dx + 0];
                acc[c][1] += k4.y * rb[c][dx + 1];
                acc[c][2] += k4.z * rb[c][dx + 2];
                acc[c][3] += k4.w * rb[c][dx + 3];
            }
        }
    }
#pragma unroll
    for (int c = 0; c < 6; ++c) {
        int ch = c0 + c;
        if (ch < NCH)
            *(float4*)(msgc + (((size_t)(b * NCH + ch)) << 14) + p0) =
                make_float4(acc[c][0], acc[c][1], acc[c][2], acc[c][3]);
    }
}

// ---- step: thread = 4-px row quad. mode 0: qb = pool4(softmax(uw*unary+up4(msg)));
//      mode 1 (final): out = uw*unary + up4(msg) as float4 stores ----
__global__ __launch_bounds__(256) void k_step(const float* __restrict__ unary,
                                              const float* __restrict__ msgc,
                                              const float* __restrict__ uwp,
                                              float* __restrict__ qb,
                                              float* __restrict__ out,
                                              int write_out) {
    int idx = blockIdx.x * 256 + threadIdx.x;   // 0..131071
    int r = idx & 3;
    int px = (idx >> 2) & 127;
    int py = (idx >> 9) & 127;
    int b = idx >> 16;
    int y = 4 * py + r;
    float uw = uwp[0];

    // rows: r<2 -> (py-1,py) fy in {0.625,0.875}; r>=2 -> (py,py+1) fy in {0.125,0.375}
    // clamping handled by duplicate rows/cols at edges (lerp degenerates correctly).
    int rA = (r < 2) ? max(py - 1, 0) : py;
    int rB = (r < 2) ? py : min(py + 1, 127);
    float fy = (r == 0) ? 0.625f : (r == 1) ? 0.875f : (r == 2) ? 0.125f : 0.375f;
    int xm1 = max(px - 1, 0), xp1 = min(px + 1, 127);
    int oA = rA << 7, oB = rB << 7;

    size_t base = (((size_t)(b * NCH)) << 18) + (y << 9) + (px << 2);
    const float* up = unary + base;
    const float* mp = msgc + (((size_t)(b * NCH)) << 14);

    float a[NCH][4];
#pragma unroll
    for (int c = 0; c < NCH; ++c) {
        float4 u4 = *(const float4*)(up + ((size_t)c << 18));
        const float* m0 = mp + ((size_t)c << 14);
        float aL = m0[oA + xm1], aM = m0[oA + px], aR = m0[oA + xp1];
        float bL = m0[oB + xm1], bM = m0[oB + px], bR = m0[oB + xp1];
        float cL = aL + (bL - aL) * fy;
        float cM = aM + (bM - aM) * fy;
        float cR = aR + (bR - aR) * fy;
        a[c][0] = uw * u4.x + cL + (cM - cL) * 0.625f;
        a[c][1] = uw * u4.y + cL + (cM - cL) * 0.875f;
        a[c][2] = uw * u4.z + cM + (cR - cM) * 0.125f;
        a[c][3] = uw * u4.w + cM + (cR - cM) * 0.375f;
    }

    if (write_out) {
        float* op = out + base;
#pragma unroll
        for (int c = 0; c < NCH; ++c)
            *(float4*)(op + ((size_t)c << 18)) = make_float4(a[c][0], a[c][1], a[c][2], a[c][3]);
        return;
    }

    float qsum[NCH];
#pragma unroll
    for (int c = 0; c < NCH; ++c) qsum[c] = 0.f;
#pragma unroll
    for (int i2 = 0; i2 < 4; ++i2) {
        float m = a[0][i2];
#pragma unroll
        for (int c = 1; c < NCH; ++c) m = fmaxf(m, a[c][i2]);
        float ss = 0.f;
#pragma unroll
        for (int c = 0; c < NCH; ++c) { float e = __expf(a[c][i2] - m); a[c][i2] = e; ss += e; }
        float inv = 1.0f / ss;
#pragma unroll
        for (int c = 0; c < NCH; ++c) qsum[c] += a[c][i2] * inv;
    }
#pragma unroll
    for (int c = 0; c < NCH; ++c) {
        float v = qsum[c];
        v += __shfl_xor(v, 1);
        v += __shfl_xor(v, 2);
        if (r == 0) qb[(((size_t)(b * NCH + c)) << 14) + (py << 7) + px] = v * 0.0625f;
    }
}

extern "C" void kernel_launch(void* const* d_in, const int* in_sizes, int n_in,
                              void* d_out, int out_size, void* d_ws, size_t ws_size,
                              hipStream_t stream) {
    const float* x  = (const float*)d_in[0];
    const float* wb = (const float*)d_in[1];
    const float* bb = (const float*)d_in[2];
    const float* uw = (const float*)d_in[3];
    const float* pw = (const float*)d_in[4];
    float* out = (float*)d_out;

    // Footprint 65.4 MB (proven to fit). prgb aliases msgc (dead after k_build_kc).
    float* ws    = (float*)d_ws;
    float* unary = ws;                    // 11,010,048 floats
    float* kc    = unary + 11010048;      // 3,964,928
    float* qb    = kc + 3964928;          // 688,128
    float* msgc  = qb + 688128;           // 688,128
    float* prgb  = msgc;                  // 98,304 (alias)

    k_conv_sm<<<512, 256, 0, stream>>>(x, wb, bb, unary, qb);
    k_pool_rgb<<<384, 256, 0, stream>>>(x, prgb);
    k_build_kc<<<15488, 256, 0, stream>>>(prgb, pw, kc);

    for (int s = 0; s < 5; ++s) {
        k_pac3<<<256, 128, 0, stream>>>(qb, kc, msgc);
        k_step<<<512, 256, 0, stream>>>(unary, msgc, uw, qb, out, (s == 4) ? 1 : 0);
    }
}

// Round 6
// 284.040 us; speedup vs baseline: 1.4102x; 1.4102x over previous
//
#include <hip/hip_runtime.h>

// B=2, H=W=512, 21 classes, 11x11 window, 4x blur. H,W % 4 == 0 -> pad=(0,0),
// avg-pool is exact 4x4 mean, post-upsample crop is identity.
#define NCH 21
#define HWP (1 << 14)   // 128*128
#define KS 11
#define KK 121
// pac v4 tiling: pooled tile 32x8, thread = 4-px strip x 1 ch, 4-ch groups
#define PTW 32
#define PTH 8
#define LROW 48                // padded cols (42 used); 48 % 32 == 16 -> conflict-free b128
#define LHGT 18
#define LPLANE (LROW * LHGT)   // 864 floats (16B-aligned, mult of 32... 864%32=0)

// ---- fused: unary = conv3x3(x,w)+b (written); qb = pool4(softmax(unary)) ----
__global__ __launch_bounds__(256) void k_conv_sm(const float* __restrict__ x,
                                                 const float* __restrict__ w,
                                                 const float* __restrict__ bias,
                                                 float* __restrict__ unary,
                                                 float* __restrict__ qb) {
    int idx = blockIdx.x * 256 + threadIdx.x;   // 0..131071
    int r = idx & 3;
    int xqi = (idx >> 2) & 127;
    int py = (idx >> 9) & 127;
    int b = idx >> 16;
    int y = 4 * py + r;
    int xq = xqi << 2;

    float p[3][3][6];
#pragma unroll
    for (int ch = 0; ch < 3; ++ch) {
        const float* xp = x + (((size_t)(b * 3 + ch)) << 18);
#pragma unroll
        for (int rr = 0; rr < 3; ++rr) {
            int yy = y + rr - 1;
            if ((unsigned)yy >= 512u) {
#pragma unroll
                for (int j = 0; j < 6; ++j) p[ch][rr][j] = 0.f;
            } else {
                const float* row = xp + (yy << 9);
                float4 v = *(const float4*)(row + xq);
                p[ch][rr][1] = v.x; p[ch][rr][2] = v.y; p[ch][rr][3] = v.z; p[ch][rr][4] = v.w;
                p[ch][rr][0] = (xq > 0) ? row[xq - 1] : 0.f;
                p[ch][rr][5] = (xq + 4 < 512) ? row[xq + 4] : 0.f;
            }
        }
    }
    float a[NCH][4];
    for (int o = 0; o < NCH; ++o) {
        const float* wp = w + o * 27;
        float bz = bias[o];
        float a0 = bz, a1 = bz, a2 = bz, a3 = bz;
#pragma unroll
        for (int ch = 0; ch < 3; ++ch)
#pragma unroll
            for (int rr = 0; rr < 3; ++rr) {
                float w0 = wp[ch * 9 + rr * 3 + 0];
                float w1 = wp[ch * 9 + rr * 3 + 1];
                float w2 = wp[ch * 9 + rr * 3 + 2];
                const float* pr = p[ch][rr];
                a0 += w0 * pr[0] + w1 * pr[1] + w2 * pr[2];
                a1 += w0 * pr[1] + w1 * pr[2] + w2 * pr[3];
                a2 += w0 * pr[2] + w1 * pr[3] + w2 * pr[4];
                a3 += w0 * pr[3] + w1 * pr[4] + w2 * pr[5];
            }
        *(float4*)(unary + (((size_t)(b * NCH + o)) << 18) + (y << 9) + xq) =
            make_float4(a0, a1, a2, a3);
        a[o][0] = a0; a[o][1] = a1; a[o][2] = a2; a[o][3] = a3;
    }
    float qsum[NCH];
#pragma unroll
    for (int c = 0; c < NCH; ++c) qsum[c] = 0.f;
#pragma unroll
    for (int i2 = 0; i2 < 4; ++i2) {
        float m = a[0][i2];
#pragma unroll
        for (int c = 1; c < NCH; ++c) m = fmaxf(m, a[c][i2]);
        float s = 0.f;
#pragma unroll
        for (int c = 0; c < NCH; ++c) { float e = __expf(a[c][i2] - m); a[c][i2] = e; s += e; }
        float inv = 1.0f / s;
#pragma unroll
        for (int c = 0; c < NCH; ++c) qsum[c] += a[c][i2] * inv;
    }
#pragma unroll
    for (int c = 0; c < NCH; ++c) {
        float v = qsum[c];
        v += __shfl_xor(v, 1);
        v += __shfl_xor(v, 2);
        if (r == 0) qb[(((size_t)(b * NCH + c)) << 14) + (py << 7) + xqi] = v * 0.0625f;
    }
}

// ---------------- pooled RGB ----------------
__global__ __launch_bounds__(256) void k_pool_rgb(const float* __restrict__ x,
                                                  float* __restrict__ prgb) {
    int idx = blockIdx.x * 256 + threadIdx.x;   // [b][3][128][128]
    int p = idx & (HWP - 1);
    int ch = (idx >> 14) % 3;
    int b = idx / (3 * HWP);
    int py = p >> 7, px = p & 127;
    const float* xp = x + (((size_t)(b * 3 + ch)) << 18);
    float s = 0.f;
#pragma unroll
    for (int r = 0; r < 4; ++r) {
        const float4 v = *(const float4*)(xp + (((4 * py + r) << 9) + 4 * px));
        s += v.x + v.y + v.z + v.w;
    }
    prgb[idx] = s * 0.0625f;
}

// ---------------- kc = pw0*exp(-.5 s_bil) + pw1*exp(-.5 s_spat) ----------------
__global__ __launch_bounds__(256) void k_build_kc(const float* __restrict__ prgb,
                                                  const float* __restrict__ pw,
                                                  float* __restrict__ kc) {
    int idx = blockIdx.x * 256 + threadIdx.x;   // [b][j][p]
    int p = idx & (HWP - 1);
    int jj = idx >> 14;                          // 0..241
    int b = (jj >= KK) ? 1 : 0;
    int j = jj - KK * b;
    int dy = j / KS, dx = j - dy * KS;
    int py = p >> 7, px = p & 127;
    float pw0 = pw[0], pw1 = pw[1];

    const float inv13 = 1.0f / 13.0f;
    float fy = (4.f * py + 1.5f) * (1.0f / 80.0f);
    float fx = (4.f * px + 1.5f) * (1.0f / 80.0f);
    const float* pb = prgb + (size_t)b * 3 * HWP;
    float r0 = pb[p] * inv13;
    float g0 = pb[HWP + p] * inv13;
    float b0 = pb[2 * HWP + p] * inv13;
    float sy = (4.f * py + 1.5f) * (1.0f / 3.0f);
    float sx = (4.f * px + 1.5f) * (1.0f / 3.0f);

    int ny = py + dy - 5;
    int nx = px + dx - 5;
    float s1, s2;
    if ((unsigned)ny < 128u && (unsigned)nx < 128u) {
        int np = (ny << 7) + nx;
        float r2 = pb[np] * inv13;
        float g2 = pb[HWP + np] * inv13;
        float b2 = pb[2 * HWP + np] * inv13;
        float dya = fy - (4.f * ny + 1.5f) * (1.0f / 80.0f);
        float dxa = fx - (4.f * nx + 1.5f) * (1.0f / 80.0f);
        float dr = r0 - r2, dg = g0 - g2, db = b0 - b2;
        s1 = dya * dya + dxa * dxa + dr * dr + dg * dg + db * db;
        float dys = sy - (4.f * ny + 1.5f) * (1.0f / 3.0f);
        float dxs = sx - (4.f * nx + 1.5f) * (1.0f / 3.0f);
        s2 = dys * dys + dxs * dxs;
    } else {
        s1 = fy * fy + fx * fx + r0 * r0 + g0 * g0 + b0 * b0;  // patch = 0
        s2 = sy * sy + sx * sx;
    }
    kc[idx] = pw0 * __expf(-0.5f * s1) + pw1 * __expf(-0.5f * s2);
}

// ---- pac v4: thread = 4-px strip x 1 ch. 768 blocks x 256 thr (12 waves/CU).
//      LDS: 4-ch halo tile, row stride 48 (conflict-free b128). ----
__global__ __launch_bounds__(256) void k_pac4(const float* __restrict__ qb,
                                              const float* __restrict__ kc,
                                              float* __restrict__ msgc) {
    int tile = blockIdx.x & 63;                  // 4 x-tiles * 16 y-tiles
    int cg = (blockIdx.x >> 6) % 6;              // channel group of 4
    int b = blockIdx.x / 384;
    int tx0 = (tile & 3) * PTW;
    int ty0 = (tile >> 2) * PTH;
    int c0 = cg * 4;

    __shared__ float lq[4 * LPLANE];             // 13824 B

    const float* qbb = qb + (((size_t)(b * NCH)) << 14);
    for (int i = threadIdx.x; i < 4 * LPLANE; i += 256) {
        int c = i / LPLANE;
        int rem = i - c * LPLANE;
        int ly = rem / LROW;
        int lx = rem - ly * LROW;
        int ch = c0 + c;
        int gy = ty0 + ly - 5, gx = tx0 + lx - 5;
        float v = 0.f;
        if (ch < NCH && lx < 42 && (unsigned)gy < 128u && (unsigned)gx < 128u)
            v = qbb[((size_t)ch << 14) + (gy << 7) + gx];
        lq[i] = v;
    }
    __syncthreads();

    int s = threadIdx.x & 63;
    int cl = threadIdx.x >> 6;                   // 0..3
    int my = s >> 3;                             // 0..7
    int mx0 = (s & 7) << 2;                      // 0,4,..,28
    int ch = c0 + cl;

    float acc0 = 0.f, acc1 = 0.f, acc2 = 0.f, acc3 = 0.f;
    int p0 = ((ty0 + my) << 7) + tx0 + mx0;
    const float* kcb = kc + (((size_t)(b * KK)) << 14) + p0;
    const float* lbase = lq + cl * LPLANE + mx0;

    for (int dy = 0; dy < KS; ++dy) {
        const float* lp = lbase + (my + dy) * LROW;
        float4 v0 = *(const float4*)(lp + 0);
        float4 v1 = *(const float4*)(lp + 4);
        float4 v2 = *(const float4*)(lp + 8);
        float4 v3 = *(const float4*)(lp + 12);
        float rb[16] = {v0.x, v0.y, v0.z, v0.w, v1.x, v1.y, v1.z, v1.w,
                        v2.x, v2.y, v2.z, v2.w, v3.x, v3.y, v3.z, v3.w};
        const float* kcrow = kcb + (((size_t)(dy * KS)) << 14);
#pragma unroll
        for (int dx = 0; dx < KS; ++dx) {
            float4 k4 = *(const float4*)(kcrow + (((size_t)dx) << 14));
            acc0 += k4.x * rb[dx + 0];
            acc1 += k4.y * rb[dx + 1];
            acc2 += k4.z * rb[dx + 2];
            acc3 += k4.w * rb[dx + 3];
        }
    }
    if (ch < NCH)
        *(float4*)(msgc + (((size_t)(b * NCH + ch)) << 14) + p0) =
            make_float4(acc0, acc1, acc2, acc3);
}

// ---- step: thread = 4-px row quad. mode 0: qb = pool4(softmax(uw*unary+up4(msg)));
//      mode 1 (final): out = uw*unary + up4(msg) as float4 stores ----
__global__ __launch_bounds__(256) void k_step(const float* __restrict__ unary,
                                              const float* __restrict__ msgc,
                                              const float* __restrict__ uwp,
                                              float* __restrict__ qb,
                                              float* __restrict__ out,
                                              int write_out) {
    int idx = blockIdx.x * 256 + threadIdx.x;   // 0..131071
    int r = idx & 3;
    int px = (idx >> 2) & 127;
    int py = (idx >> 9) & 127;
    int b = idx >> 16;
    int y = 4 * py + r;
    float uw = uwp[0];

    int rA = (r < 2) ? max(py - 1, 0) : py;
    int rB = (r < 2) ? py : min(py + 1, 127);
    float fy = (r == 0) ? 0.625f : (r == 1) ? 0.875f : (r == 2) ? 0.125f : 0.375f;
    int xm1 = max(px - 1, 0), xp1 = min(px + 1, 127);
    int oA = rA << 7, oB = rB << 7;

    size_t base = (((size_t)(b * NCH)) << 18) + (y << 9) + (px << 2);
    const float* up = unary + base;
    const float* mp = msgc + (((size_t)(b * NCH)) << 14);

    float a[NCH][4];
#pragma unroll
    for (int c = 0; c < NCH; ++c) {
        float4 u4 = *(const float4*)(up + ((size_t)c << 18));
        const float* m0 = mp + ((size_t)c << 14);
        float aL = m0[oA + xm1], aM = m0[oA + px], aR = m0[oA + xp1];
        float bL = m0[oB + xm1], bM = m0[oB + px], bR = m0[oB + xp1];
        float cL = aL + (bL - aL) * fy;
        float cM = aM + (bM - aM) * fy;
        float cR = aR + (bR - aR) * fy;
        a[c][0] = uw * u4.x + cL + (cM - cL) * 0.625f;
        a[c][1] = uw * u4.y + cL + (cM - cL) * 0.875f;
        a[c][2] = uw * u4.z + cM + (cR - cM) * 0.125f;
        a[c][3] = uw * u4.w + cM + (cR - cM) * 0.375f;
    }

    if (write_out) {
        float* op = out + base;
#pragma unroll
        for (int c = 0; c < NCH; ++c)
            *(float4*)(op + ((size_t)c << 18)) = make_float4(a[c][0], a[c][1], a[c][2], a[c][3]);
        return;
    }

    float qsum[NCH];
#pragma unroll
    for (int c = 0; c < NCH; ++c) qsum[c] = 0.f;
#pragma unroll
    for (int i2 = 0; i2 < 4; ++i2) {
        float m = a[0][i2];
#pragma unroll
        for (int c = 1; c < NCH; ++c) m = fmaxf(m, a[c][i2]);
        float ss = 0.f;
#pragma unroll
        for (int c = 0; c < NCH; ++c) { float e = __expf(a[c][i2] - m); a[c][i2] = e; ss += e; }
        float inv = 1.0f / ss;
#pragma unroll
        for (int c = 0; c < NCH; ++c) qsum[c] += a[c][i2] * inv;
    }
#pragma unroll
    for (int c = 0; c < NCH; ++c) {
        float v = qsum[c];
        v += __shfl_xor(v, 1);
        v += __shfl_xor(v, 2);
        if (r == 0) qb[(((size_t)(b * NCH + c)) << 14) + (py << 7) + px] = v * 0.0625f;
    }
}

extern "C" void kernel_launch(void* const* d_in, const int* in_sizes, int n_in,
                              void* d_out, int out_size, void* d_ws, size_t ws_size,
                              hipStream_t stream) {
    const float* x  = (const float*)d_in[0];
    const float* wb = (const float*)d_in[1];
    const float* bb = (const float*)d_in[2];
    const float* uw = (const float*)d_in[3];
    const float* pw = (const float*)d_in[4];
    float* out = (float*)d_out;

    // Footprint 65.4 MB (proven to fit). prgb aliases msgc (dead after k_build_kc).
    float* ws    = (float*)d_ws;
    float* unary = ws;                    // 11,010,048 floats
    float* kc    = unary + 11010048;      // 3,964,928
    float* qb    = kc + 3964928;          // 688,128
    float* msgc  = qb + 688128;           // 688,128
    float* prgb  = msgc;                  // 98,304 (alias)

    k_conv_sm<<<512, 256, 0, stream>>>(x, wb, bb, unary, qb);
    k_pool_rgb<<<384, 256, 0, stream>>>(x, prgb);
    k_build_kc<<<15488, 256, 0, stream>>>(prgb, pw, kc);

    for (int s = 0; s < 5; ++s) {
        k_pac4<<<768, 256, 0, stream>>>(qb, kc, msgc);
        k_step<<<512, 256, 0, stream>>>(unary, msgc, uw, qb, out, (s == 4) ? 1 : 0);
    }
}